// Round 12
// baseline (137.617 us; speedup 1.0000x reference)
//
#include <hip/hip_runtime.h>

#define N_NODES 100000
#define N_EDGES 3200000
#define F_IN 128
#define F_HID 16

// fine buckets (consumer-facing)
#define BK_LG 7
#define BK_NODES 128
#define NB ((N_NODES + BK_NODES - 1) / BK_NODES)      // 782
#define BCAPF 4736                                    // avg 4093, +10 sigma
// coarse buckets (pass-1)
#define CLG 10
#define CNODES 1024
#define NBC ((N_NODES + CNODES - 1) / CNODES)         // 98
#define NBC_P 128
#define BCAPC 34816                                   // avg 32768, +11 sigma
#define CHUNK1 2048                                   // pass-1 chunk (256 threads)
#define NCH1 ((N_EDGES + CHUNK1 - 1) / CHUNK1)        // 1563
#define CHUNKM 2048                                   // pass-2 chunk (256 threads)
#define CPB2 ((BCAPC + CHUNKM - 1) / CHUNKM)          // 17
#define NMB (NBC * CPB2)                              // 1666 bin2-role blocks
#define NXB ((N_NODES + 63) / 64)                     // 1563 xw0 tiles
#define PAIRED (2 * NXB)                              // 3126 (NXB < NMB)
#define GRID_MID (NMB + NXB)                          // 3229
#define CUR_STRIDE 16

__device__ __forceinline__ unsigned short f2bf_rne(float f) {
    unsigned u = __float_as_uint(f);
    u += 0x7FFFu + ((u >> 16) & 1u);
    return (unsigned short)(u >> 16);
}

// ---------------------------------------------------------------------------
// K1: pass-1 bin into coarse 1024-node buckets. Standalone (critical path),
// 21KB LDS -> 7 blocks/CU. Packed edge: .x = w, .y = src | (dlc << 17).
// ---------------------------------------------------------------------------
__global__ __launch_bounds__(256) void k_bin1(const int* __restrict__ src,
                                              const int* __restrict__ dst,
                                              const float* __restrict__ ew,
                                              int* __restrict__ cursorC,
                                              int2* __restrict__ ebinC) {
    __shared__ int2 stage[CHUNK1];
    __shared__ unsigned char sbid[CHUNK1];
    __shared__ int cnt[NBC_P], excl[NBC_P], run[NBC_P], gb[NBC_P], alw[NBC_P];
    __shared__ int wtot[2];
    const int tid = threadIdx.x;
    const int e0  = blockIdx.x * CHUNK1;
    const int nch = min(CHUNK1, N_EDGES - e0);

    for (int i = tid; i < NBC_P; i += 256) cnt[i] = 0;
    __syncthreads();

    int es[8], eb[8], edl[8]; float ww[8];
    #pragma unroll
    for (int k = 0; k < 8; ++k) {
        int idx = k * 256 + tid;
        if (idx < nch) {
            int e = e0 + idx;
            int d = dst[e];
            es[k]  = src[e];
            ww[k]  = ew[e];
            eb[k]  = d >> CLG;
            edl[k] = d & (CNODES - 1);
            atomicAdd(&cnt[eb[k]], 1);
        } else {
            eb[k] = -1;
        }
    }
    __syncthreads();

    // exclusive scan of cnt[0..128) via 2-wave shuffle
    {
        const int lane = tid & 63;
        int inc = 0, dv_ = 0;
        if (tid < NBC_P) {
            dv_ = cnt[tid];
            inc = dv_;
            #pragma unroll
            for (int off = 1; off < 64; off <<= 1) {
                int t = __shfl_up(inc, off);
                if (lane >= off) inc += t;
            }
            if (lane == 63) wtot[tid >> 6] = inc;
        }
        __syncthreads();
        if (tid < NBC_P) {
            int base = (tid >= 64) ? wtot[0] : 0;
            excl[tid] = base + inc - dv_;
        }
    }
    __syncthreads();

    if (tid < NBC) {
        int c = cnt[tid];
        if (c > 0) {
            int old = atomicAdd(&cursorC[tid * CUR_STRIDE], c);
            int a = BCAPC - old;
            a = (a < 0) ? 0 : ((a > c) ? c : a);
            alw[tid] = a;
            gb[tid]  = tid * BCAPC + old;
        } else {
            alw[tid] = 0;
            gb[tid]  = tid * BCAPC;
        }
        run[tid] = 0;
    }
    __syncthreads();

    #pragma unroll
    for (int k = 0; k < 8; ++k) {
        if (eb[k] >= 0) {
            int b = eb[k];
            int p = excl[b] + atomicAdd(&run[b], 1);
            stage[p] = make_int2(__float_as_int(ww[k]), es[k] | (edl[k] << 17));
            sbid[p]  = (unsigned char)b;
        }
    }
    __syncthreads();

    for (int s = tid; s < nch; s += 256) {
        int b   = sbid[s];
        int off = s - excl[b];
        if (off < alw[b]) ebinC[(size_t)gb[b] + off] = stage[s];
    }
}

// ---------------------------------------------------------------------------
// K2 (fused, 24.8KB union -> 6 blocks/CU):
//   role A (bin2): split one 2048-edge coarse chunk 8-ways into fine buckets
//                  + per-node degree histogram (LDS dcnt -> striped atomics)
//   role B (xw0):  64-row x@W0 tile (x staged bf16) -> z0b
// xw0's streaming read overlaps bin2's scatter phase.
// ---------------------------------------------------------------------------
__global__ __launch_bounds__(256) void k_mid(const int* __restrict__ cursorC,
                                             const int2* __restrict__ ebinC,
                                             int* __restrict__ cursorF,
                                             int2* __restrict__ ebinF,
                                             int* __restrict__ deg,
                                             const float* __restrict__ x,
                                             const float* __restrict__ W0,
                                             unsigned short* __restrict__ z0b) {
    __shared__ __align__(16) char smem[24832];
    const int tid = threadIdx.x;
    const int bid = blockIdx.x;
    int rid; bool isBin;
    if (bid < PAIRED) { isBin = (bid & 1) == 0; rid = bid >> 1; }
    else              { isBin = true; rid = NXB + (bid - PAIRED); }

    if (!isBin) {
        // ------------------- xw0 role (bf16-staged x) -------------------
        unsigned short* xsb = (unsigned short*)smem;      // [64][130] bf16
        float* w0s = (float*)(smem + 16640);              // [128*16] f32
        for (int i = tid; i < F_IN * F_HID; i += 256) w0s[i] = W0[i];
        const int row0 = rid * 64;
        for (int i = tid; i < 64 * 32; i += 256) {
            int r = i >> 5, c4 = i & 31;
            float4 v = make_float4(0.f, 0.f, 0.f, 0.f);
            int row = row0 + r;
            if (row < N_NODES) v = ((const float4*)(x + (size_t)row * F_IN))[c4];
            *(ushort2*)(xsb + r * 130 + c4 * 4)     = make_ushort2(f2bf_rne(v.x), f2bf_rne(v.y));
            *(ushort2*)(xsb + r * 130 + c4 * 4 + 2) = make_ushort2(f2bf_rne(v.z), f2bf_rne(v.w));
        }
        __syncthreads();
        const int r  = tid & 63;
        const int cg = tid >> 6;
        float a0 = 0.f, a1 = 0.f, a2 = 0.f, a3 = 0.f;
        #pragma unroll 4
        for (int k = 0; k < F_IN; k += 2) {
            unsigned u = *(const unsigned*)(xsb + r * 130 + k);
            float xv0 = __uint_as_float(u << 16);
            float xv1 = __uint_as_float(u & 0xFFFF0000u);
            const float* wr0 = w0s + k * F_HID + cg * 4;
            const float* wr1 = wr0 + F_HID;
            a0 = fmaf(xv0, wr0[0], a0); a1 = fmaf(xv0, wr0[1], a1);
            a2 = fmaf(xv0, wr0[2], a2); a3 = fmaf(xv0, wr0[3], a3);
            a0 = fmaf(xv1, wr1[0], a0); a1 = fmaf(xv1, wr1[1], a1);
            a2 = fmaf(xv1, wr1[2], a2); a3 = fmaf(xv1, wr1[3], a3);
        }
        int row = row0 + r;
        if (row < N_NODES) {
            ushort4 p = make_ushort4(f2bf_rne(a0), f2bf_rne(a1),
                                     f2bf_rne(a2), f2bf_rne(a3));
            *(ushort4*)(z0b + (size_t)row * F_HID + cg * 4) = p;
        }
    } else {
        // ------------------- bin2 role -------------------
        int2* stage = (int2*)smem;                             // 16384 B
        unsigned char* sbid = (unsigned char*)(smem + 16384);  // 2048 B
        int* dcnt   = (int*)(smem + 18432);                    // 1024 ints
        int* cntw   = (int*)(smem + 22528);                    // 32
        int* runw   = (int*)(smem + 22656);                    // 32
        int* base   = (int*)(smem + 22784);                    // 32
        int* totals = (int*)(smem + 23040);                    // 8
        int* excl_s = (int*)(smem + 23072);                    // 8
        int* gb8    = (int*)(smem + 23104);                    // 8
        int* alw8   = (int*)(smem + 23136);                    // 8
        const int wid = tid >> 6;                              // 0..3
        const int c   = rid / CPB2;
        const int ck  = rid % CPB2;
        const int ecnt = min(cursorC[c * CUR_STRIDE], BCAPC);
        const int beg  = ck * CHUNKM;
        const int n2   = min(CHUNKM, ecnt - beg);
        if (n2 <= 0) return;                                   // uniform exit
        const int2* eC = ebinC + (size_t)c * BCAPC + beg;

        if (tid < 32) { cntw[tid] = 0; runw[tid] = 0; }
        for (int i = tid; i < CNODES; i += 256) dcnt[i] = 0;
        __syncthreads();

        int fid[8]; int2 pk[8];
        #pragma unroll
        for (int k = 0; k < 8; ++k) {
            int idx = k * 256 + tid;
            if (idx < n2) {
                int2 e = eC[idx];
                int dlc = e.y >> 17;
                int f   = dlc >> BK_LG;
                fid[k]  = f;
                pk[k]   = make_int2(e.x, (e.y & 0x1FFFF) | ((dlc & (BK_NODES - 1)) << 17));
                atomicAdd(&cntw[f * 4 + wid], 1);
                atomicAdd(&dcnt[dlc], 1);
            } else {
                fid[k] = -1;
            }
        }
        __syncthreads();

        if (tid < 8) {
            int t = 0;
            #pragma unroll
            for (int w = 0; w < 4; ++w) t += cntw[tid * 4 + w];
            totals[tid] = t;
        }
        __syncthreads();
        if (tid < 8) {
            int e = 0;
            for (int f = 0; f < 8; ++f) if (f < tid) e += totals[f];
            excl_s[tid] = e;
            int t = totals[tid];
            int fb = c * 8 + tid;
            if (t > 0 && fb < NB) {
                int old = atomicAdd(&cursorF[fb * CUR_STRIDE], t);
                int a = BCAPF - old;
                a = (a < 0) ? 0 : ((a > t) ? t : a);
                alw8[tid] = a;
                gb8[tid]  = fb * BCAPF + old;
            } else {
                alw8[tid] = 0;
                gb8[tid]  = 0;
            }
        }
        __syncthreads();
        if (tid < 32) {
            int f = tid >> 2, w = tid & 3;
            int bb = excl_s[f];
            for (int w2 = 0; w2 < 4; ++w2) if (w2 < w) bb += cntw[f * 4 + w2];
            base[tid] = bb;
        }
        __syncthreads();

        #pragma unroll
        for (int k = 0; k < 8; ++k) {
            if (fid[k] >= 0) {
                int slot = fid[k] * 4 + wid;
                int p = base[slot] + atomicAdd(&runw[slot], 1);
                stage[p] = pk[k];
                sbid[p]  = (unsigned char)fid[k];
            }
        }
        __syncthreads();

        for (int s = tid; s < n2; s += 256) {
            int f   = sbid[s];
            int off = s - excl_s[f];
            if (off < alw8[f]) ebinF[(size_t)gb8[f] + off] = stage[s];
        }

        // flush per-node degree counts (striped, ~1K atomics/block)
        for (int i = tid; i < CNODES; i += 256) {
            int d = dcnt[i];
            int v = c * CNODES + i;
            if (d > 0 && v < N_NODES) atomicAdd(&deg[v], d);
        }
    }
}

// ---------------------------------------------------------------------------
// K3: gather layer 0 with direct-place LDS sort (deg precomputed).
// ---------------------------------------------------------------------------
__global__ __launch_bounds__(512) void k_sg0(const int* __restrict__ deg,
                                             const int2* __restrict__ ebinF,
                                             const unsigned short* __restrict__ z0b,
                                             const float* __restrict__ b0,
                                             const float* __restrict__ W1,
                                             float* __restrict__ z1) {
    __shared__ int2 sorted[BCAPF];               // 37.9 KB
    __shared__ int scn[BK_NODES], dg[BK_NODES], run[BK_NODES];
    __shared__ int wtot[2], ecnt_s;
    __shared__ float b0s[16], w1s[16];
    const int tid  = threadIdx.x;
    const int lane = tid & 63, wid = tid >> 6;
    const int b    = blockIdx.x;
    if (tid < 16) { b0s[tid] = b0[tid]; w1s[tid] = W1[tid]; }

    int inc = 0, d_ = 0;
    if (tid < BK_NODES) {
        int v = b * BK_NODES + tid;
        d_ = (v < N_NODES) ? deg[v] : 0;
        dg[tid]  = d_;
        run[tid] = 0;
        inc = d_;
        #pragma unroll
        for (int off = 1; off < 64; off <<= 1) {
            int t = __shfl_up(inc, off);
            if (lane >= off) inc += t;
        }
        if (lane == 63) wtot[tid >> 6] = inc;
    }
    __syncthreads();
    if (tid < BK_NODES) {
        int base = (tid >= 64) ? wtot[0] : 0;
        scn[tid] = base + inc - d_;
        if (tid == BK_NODES - 1) ecnt_s = min(base + inc, BCAPF);
    }
    __syncthreads();

    const int ecnt = ecnt_s;
    const int2* eb = ebinF + (size_t)b * BCAPF;
    for (int i = tid; i < ecnt; i += 512) {
        int2 e  = eb[i];
        int  dl = e.y >> 17;
        int  p  = scn[dl] + atomicAdd(&run[dl], 1);
        if (p < BCAPF) sorted[p] = e;
    }
    __syncthreads();

    for (int n = wid; n < BK_NODES; n += 8) {
        const int v = b * BK_NODES + n;
        if (v >= N_NODES) continue;
        const int beg = scn[n];
        const int end = min(beg + dg[n], BCAPF);
        const int dv  = end - beg;
        const int f2  = lane & 7;
        const int g   = lane >> 3;
        float acc0 = 0.f, acc1 = 0.f;
        for (int j = g; j < dv; j += 16) {
            int2 e0 = sorted[beg + j];
            int  j1 = j + 8;
            int2 e1 = (j1 < dv) ? sorted[beg + j1] : make_int2(0, 0);
            unsigned u0 = *(const unsigned*)(z0b + (size_t)(e0.y & 0x1FFFF) * F_HID + f2 * 2);
            unsigned u1 = *(const unsigned*)(z0b + (size_t)(e1.y & 0x1FFFF) * F_HID + f2 * 2);
            float w0 = __int_as_float(e0.x), w1 = __int_as_float(e1.x);
            acc0 = fmaf(__uint_as_float(u0 << 16),         w0, acc0);
            acc1 = fmaf(__uint_as_float(u0 & 0xFFFF0000u), w0, acc1);
            acc0 = fmaf(__uint_as_float(u1 << 16),         w1, acc0);
            acc1 = fmaf(__uint_as_float(u1 & 0xFFFF0000u), w1, acc1);
        }
        acc0 += __shfl_xor(acc0, 8);  acc1 += __shfl_xor(acc1, 8);
        acc0 += __shfl_xor(acc0, 16); acc1 += __shfl_xor(acc1, 16);
        acc0 += __shfl_xor(acc0, 32); acc1 += __shfl_xor(acc1, 32);
        float cc = fmaxf(acc0 + b0s[f2 * 2], 0.f) * w1s[f2 * 2]
                 + fmaxf(acc1 + b0s[f2 * 2 + 1], 0.f) * w1s[f2 * 2 + 1];
        cc += __shfl_xor(cc, 1);
        cc += __shfl_xor(cc, 2);
        cc += __shfl_xor(cc, 4);
        if (lane == 0) z1[v] = cc;
    }
}

// ---------------------------------------------------------------------------
// K4: layer 1 from bucket-grouped ebinF: 1 LDS atomic/edge + fused sigmoid.
// ---------------------------------------------------------------------------
__global__ __launch_bounds__(256) void k_g1(const int* __restrict__ cursorF,
                                            const int2* __restrict__ ebinF,
                                            const float* __restrict__ z1,
                                            const float* __restrict__ b1,
                                            float* __restrict__ out) {
    __shared__ float acc[BK_NODES];
    const int tid = threadIdx.x;
    const int b   = blockIdx.x;
    if (tid < BK_NODES) acc[tid] = 0.f;
    __syncthreads();
    const int   ecnt = min(cursorF[b * CUR_STRIDE], BCAPF);
    const int2* eb   = ebinF + (size_t)b * BCAPF;
    for (int i = tid; i < ecnt; i += 512) {
        int2 e0 = eb[i];
        int  i1 = i + 256;
        int2 e1 = (i1 < ecnt) ? eb[i1] : make_int2(0, 0);
        float m0 = z1[e0.y & 0x1FFFF] * __int_as_float(e0.x);
        float m1 = z1[e1.y & 0x1FFFF] * __int_as_float(e1.x);
        atomicAdd(&acc[e0.y >> 17], m0);
        if (i1 < ecnt) atomicAdd(&acc[e1.y >> 17], m1);
    }
    __syncthreads();
    if (tid < BK_NODES) {
        int v = b * BK_NODES + tid;
        if (v < N_NODES) out[v] = 1.f / (1.f + expf(-(acc[tid] + b1[0])));
    }
}

extern "C" void kernel_launch(void* const* d_in, const int* in_sizes, int n_in,
                              void* d_out, int out_size, void* d_ws, size_t ws_size,
                              hipStream_t stream) {
    const float* x   = (const float*)d_in[0];
    const int*   src = (const int*)d_in[1];
    const int*   dst = (const int*)d_in[2];
    const float* ew  = (const float*)d_in[3];
    const float* W0  = (const float*)d_in[4];
    const float* b0  = (const float*)d_in[5];
    const float* W1  = (const float*)d_in[6];
    const float* b1  = (const float*)d_in[7];
    float* out = (float*)d_out;

    // Workspace (~61 MB): z0b | z1 | deg | cursorC | cursorF | ebinC | ebinF
    unsigned short* z0b = (unsigned short*)d_ws;                 // 3.2 MB
    float* z1      = (float*)(z0b + (size_t)N_NODES * F_HID);    // 400 KB
    int*   deg     = (int*)(z1 + N_NODES);                       // 400 KB
    int*   cursorC = deg + N_NODES;                              // 6.3 KB
    int*   cursorF = cursorC + NBC * CUR_STRIDE;                 // 50 KB
    int2*  ebinC   = (int2*)(cursorF + NB * CUR_STRIDE);         // 27.3 MB
    int2*  ebinF   = ebinC + (size_t)NBC * BCAPC;                // 29.6 MB

    hipMemsetAsync(deg, 0,
                   ((size_t)N_NODES + (size_t)(NBC + NB) * CUR_STRIDE) * sizeof(int),
                   stream);

    k_bin1<<<NCH1, 256, 0, stream>>>(src, dst, ew, cursorC, ebinC);
    k_mid <<<GRID_MID, 256, 0, stream>>>(cursorC, ebinC, cursorF, ebinF, deg,
                                         x, W0, z0b);
    k_sg0 <<<NB, 512, 0, stream>>>(deg, ebinF, z0b, b0, W1, z1);
    k_g1  <<<NB, 256, 0, stream>>>(cursorF, ebinF, z1, b1, out);
}

// Round 13
// 125.596 us; speedup vs baseline: 1.0957x; 1.0957x over previous
//
#include <hip/hip_runtime.h>

#define N_NODES 100000
#define N_EDGES 3200000
#define F_IN 128
#define F_HID 16

// fine buckets (consumer-facing)
#define BK_LG 7
#define BK_NODES 128
#define NB ((N_NODES + BK_NODES - 1) / BK_NODES)      // 782
#define BCAPF 4736                                    // avg 4093, +10 sigma
// coarse buckets (pass-1)
#define CLG 10
#define CNODES 1024
#define NBC ((N_NODES + CNODES - 1) / CNODES)         // 98
#define NBC_P 128
#define BCAPC 34816                                   // avg 32768, +11 sigma
#define CHUNK1 4096                                   // pass-1 chunk (512 threads)
#define NCH1 ((N_EDGES + CHUNK1 - 1) / CHUNK1)        // 782
#define CHUNKM 2048                                   // pass-2 chunk (256 threads)
#define CPB2 ((BCAPC + CHUNKM - 1) / CHUNKM)          // 17
#define NMB (NBC * CPB2)                              // 1666 bin2-role blocks
#define NXB ((N_NODES + 63) / 64)                     // 1563 xw0 tiles
#define PAIRED (2 * NXB)                              // 3126
#define GRID_MID (NMB + NXB)                          // 3229
#define CUR_STRIDE 16

__device__ __forceinline__ unsigned short f2bf_rne(float f) {
    unsigned u = __float_as_uint(f);
    u += 0x7FFFu + ((u >> 16) & 1u);
    return (unsigned short)(u >> 16);
}

// ---------------------------------------------------------------------------
// K1: pass-1 bin into coarse 1024-node buckets. 4096 edges/block, 512 thr,
// wave-replicated count/run counters (no cross-wave LDS atomic contention).
// Packed edge: .x = w, .y = src | (dlc << 17).
// ---------------------------------------------------------------------------
__global__ __launch_bounds__(512) void k_bin1(const int* __restrict__ src,
                                              const int* __restrict__ dst,
                                              const float* __restrict__ ew,
                                              int* __restrict__ cursorC,
                                              int2* __restrict__ ebinC) {
    __shared__ int2 stage[CHUNK1];                 // 32 KB
    __shared__ unsigned char sbid[CHUNK1];         // 4 KB
    __shared__ int cntw[NBC_P * 8];                // 4 KB (bucket x wave)
    __shared__ int runw[NBC_P * 8];                // 4 KB
    __shared__ int basew[NBC_P * 8];               // 4 KB
    __shared__ int cnt[NBC_P], excl[NBC_P], gb[NBC_P], alw[NBC_P];
    __shared__ int wtot[2];
    const int tid  = threadIdx.x;
    const int lane = tid & 63, wid = tid >> 6;     // 8 waves
    const int e0   = blockIdx.x * CHUNK1;
    const int nch  = min(CHUNK1, N_EDGES - e0);

    for (int i = tid; i < NBC_P * 8; i += 512) { cntw[i] = 0; runw[i] = 0; }
    __syncthreads();

    // load + per-wave count
    int es[8], eb[8], edl[8]; float ww[8];
    #pragma unroll
    for (int k = 0; k < 8; ++k) {
        int idx = k * 512 + tid;
        if (idx < nch) {
            int e = e0 + idx;
            int d = dst[e];
            es[k]  = src[e];
            ww[k]  = ew[e];
            eb[k]  = d >> CLG;
            edl[k] = d & (CNODES - 1);
            atomicAdd(&cntw[eb[k] * 8 + wid], 1);
        } else {
            eb[k] = -1;
        }
    }
    __syncthreads();

    // per-bucket totals
    if (tid < NBC_P) {
        int t = 0;
        #pragma unroll
        for (int w = 0; w < 8; ++w) t += cntw[tid * 8 + w];
        cnt[tid] = t;
    }
    __syncthreads();

    // exclusive scan of cnt[0..128) via 2-wave shuffle; cursor reserve
    int inc = 0, c_ = 0;
    if (tid < NBC_P) {
        c_ = cnt[tid];
        inc = c_;
        #pragma unroll
        for (int off = 1; off < 64; off <<= 1) {
            int t = __shfl_up(inc, off);
            if (lane >= off) inc += t;
        }
        if (lane == 63) wtot[tid >> 6] = inc;
    }
    __syncthreads();
    if (tid < NBC_P) {
        int base = (tid >= 64) ? wtot[0] : 0;
        excl[tid] = base + inc - c_;
    }
    if (tid < NBC) {
        int c = cnt[tid];
        if (c > 0) {
            int old = atomicAdd(&cursorC[tid * CUR_STRIDE], c);
            int a = BCAPC - old;
            a = (a < 0) ? 0 : ((a > c) ? c : a);
            alw[tid] = a;
            gb[tid]  = tid * BCAPC + old;
        } else {
            alw[tid] = 0;
            gb[tid]  = tid * BCAPC;
        }
    }
    __syncthreads();

    // per-(bucket,wave) bases
    if (tid < NBC_P) {
        int bb = excl[tid];
        #pragma unroll
        for (int w = 0; w < 8; ++w) { basew[tid * 8 + w] = bb; bb += cntw[tid * 8 + w]; }
    }
    __syncthreads();

    // place (contention only within a wave: <1 same-bucket lane on average)
    #pragma unroll
    for (int k = 0; k < 8; ++k) {
        if (eb[k] >= 0) {
            int b = eb[k];
            int p = basew[b * 8 + wid] + atomicAdd(&runw[b * 8 + wid], 1);
            stage[p] = make_int2(__float_as_int(ww[k]), es[k] | (edl[k] << 17));
            sbid[p]  = (unsigned char)b;
        }
    }
    __syncthreads();

    // flush: runs of ~42 edges per bucket -> near-coalesced
    for (int s = tid; s < nch; s += 512) {
        int b   = sbid[s];
        int off = s - excl[b];
        if (off < alw[b]) ebinC[(size_t)gb[b] + off] = stage[s];
    }
}

// ---------------------------------------------------------------------------
// K2 (fused, 24.8KB union -> 6 blocks/CU):
//   role A (bin2): split one 2048-edge coarse chunk 8-ways into fine buckets
//                  + per-node degree histogram (LDS dcnt -> striped atomics)
//   role B (xw0):  64-row x@W0 tile (x staged bf16) -> z0b
// ---------------------------------------------------------------------------
__global__ __launch_bounds__(256) void k_mid(const int* __restrict__ cursorC,
                                             const int2* __restrict__ ebinC,
                                             int* __restrict__ cursorF,
                                             int2* __restrict__ ebinF,
                                             int* __restrict__ deg,
                                             const float* __restrict__ x,
                                             const float* __restrict__ W0,
                                             unsigned short* __restrict__ z0b) {
    __shared__ __align__(16) char smem[24832];
    const int tid = threadIdx.x;
    const int bid = blockIdx.x;
    int rid; bool isBin;
    if (bid < PAIRED) { isBin = (bid & 1) == 0; rid = bid >> 1; }
    else              { isBin = true; rid = NXB + (bid - PAIRED); }

    if (!isBin) {
        // ------------------- xw0 role (bf16-staged x) -------------------
        unsigned short* xsb = (unsigned short*)smem;      // [64][130] bf16
        float* w0s = (float*)(smem + 16640);              // [128*16] f32
        for (int i = tid; i < F_IN * F_HID; i += 256) w0s[i] = W0[i];
        const int row0 = rid * 64;
        for (int i = tid; i < 64 * 32; i += 256) {
            int r = i >> 5, c4 = i & 31;
            float4 v = make_float4(0.f, 0.f, 0.f, 0.f);
            int row = row0 + r;
            if (row < N_NODES) v = ((const float4*)(x + (size_t)row * F_IN))[c4];
            *(ushort2*)(xsb + r * 130 + c4 * 4)     = make_ushort2(f2bf_rne(v.x), f2bf_rne(v.y));
            *(ushort2*)(xsb + r * 130 + c4 * 4 + 2) = make_ushort2(f2bf_rne(v.z), f2bf_rne(v.w));
        }
        __syncthreads();
        const int r  = tid & 63;
        const int cg = tid >> 6;
        float a0 = 0.f, a1 = 0.f, a2 = 0.f, a3 = 0.f;
        #pragma unroll 4
        for (int k = 0; k < F_IN; k += 2) {
            unsigned u = *(const unsigned*)(xsb + r * 130 + k);
            float xv0 = __uint_as_float(u << 16);
            float xv1 = __uint_as_float(u & 0xFFFF0000u);
            const float* wr0 = w0s + k * F_HID + cg * 4;
            const float* wr1 = wr0 + F_HID;
            a0 = fmaf(xv0, wr0[0], a0); a1 = fmaf(xv0, wr0[1], a1);
            a2 = fmaf(xv0, wr0[2], a2); a3 = fmaf(xv0, wr0[3], a3);
            a0 = fmaf(xv1, wr1[0], a0); a1 = fmaf(xv1, wr1[1], a1);
            a2 = fmaf(xv1, wr1[2], a2); a3 = fmaf(xv1, wr1[3], a3);
        }
        int row = row0 + r;
        if (row < N_NODES) {
            ushort4 p = make_ushort4(f2bf_rne(a0), f2bf_rne(a1),
                                     f2bf_rne(a2), f2bf_rne(a3));
            *(ushort4*)(z0b + (size_t)row * F_HID + cg * 4) = p;
        }
    } else {
        // ------------------- bin2 role -------------------
        int2* stage = (int2*)smem;                             // 16384 B
        unsigned char* sbid = (unsigned char*)(smem + 16384);  // 2048 B
        int* dcnt   = (int*)(smem + 18432);                    // 1024 ints
        int* cntw   = (int*)(smem + 22528);                    // 32
        int* runw   = (int*)(smem + 22656);                    // 32
        int* base   = (int*)(smem + 22784);                    // 32
        int* totals = (int*)(smem + 23040);                    // 8
        int* excl_s = (int*)(smem + 23072);                    // 8
        int* gb8    = (int*)(smem + 23104);                    // 8
        int* alw8   = (int*)(smem + 23136);                    // 8
        const int wid = tid >> 6;                              // 0..3
        const int c   = rid / CPB2;
        const int ck  = rid % CPB2;
        const int ecnt = min(cursorC[c * CUR_STRIDE], BCAPC);
        const int beg  = ck * CHUNKM;
        const int n2   = min(CHUNKM, ecnt - beg);
        if (n2 <= 0) return;                                   // uniform exit
        const int2* eC = ebinC + (size_t)c * BCAPC + beg;

        if (tid < 32) { cntw[tid] = 0; runw[tid] = 0; }
        for (int i = tid; i < CNODES; i += 256) dcnt[i] = 0;
        __syncthreads();

        int fid[8]; int2 pk[8];
        #pragma unroll
        for (int k = 0; k < 8; ++k) {
            int idx = k * 256 + tid;
            if (idx < n2) {
                int2 e = eC[idx];
                int dlc = e.y >> 17;
                int f   = dlc >> BK_LG;
                fid[k]  = f;
                pk[k]   = make_int2(e.x, (e.y & 0x1FFFF) | ((dlc & (BK_NODES - 1)) << 17));
                atomicAdd(&cntw[f * 4 + wid], 1);
                atomicAdd(&dcnt[dlc], 1);
            } else {
                fid[k] = -1;
            }
        }
        __syncthreads();

        if (tid < 8) {
            int t = 0;
            #pragma unroll
            for (int w = 0; w < 4; ++w) t += cntw[tid * 4 + w];
            totals[tid] = t;
        }
        __syncthreads();
        if (tid < 8) {
            int e = 0;
            for (int f = 0; f < 8; ++f) if (f < tid) e += totals[f];
            excl_s[tid] = e;
            int t = totals[tid];
            int fb = c * 8 + tid;
            if (t > 0 && fb < NB) {
                int old = atomicAdd(&cursorF[fb * CUR_STRIDE], t);
                int a = BCAPF - old;
                a = (a < 0) ? 0 : ((a > t) ? t : a);
                alw8[tid] = a;
                gb8[tid]  = fb * BCAPF + old;
            } else {
                alw8[tid] = 0;
                gb8[tid]  = 0;
            }
        }
        __syncthreads();
        if (tid < 32) {
            int f = tid >> 2, w = tid & 3;
            int bb = excl_s[f];
            for (int w2 = 0; w2 < 4; ++w2) if (w2 < w) bb += cntw[f * 4 + w2];
            base[tid] = bb;
        }
        __syncthreads();

        #pragma unroll
        for (int k = 0; k < 8; ++k) {
            if (fid[k] >= 0) {
                int slot = fid[k] * 4 + wid;
                int p = base[slot] + atomicAdd(&runw[slot], 1);
                stage[p] = pk[k];
                sbid[p]  = (unsigned char)fid[k];
            }
        }
        __syncthreads();

        for (int s = tid; s < n2; s += 256) {
            int f   = sbid[s];
            int off = s - excl_s[f];
            if (off < alw8[f]) ebinF[(size_t)gb8[f] + off] = stage[s];
        }

        for (int i = tid; i < CNODES; i += 256) {
            int d = dcnt[i];
            int v = c * CNODES + i;
            if (d > 0 && v < N_NODES) atomicAdd(&deg[v], d);
        }
    }
}

// ---------------------------------------------------------------------------
// K3: gather layer 0 with direct-place LDS sort (deg precomputed).
// ---------------------------------------------------------------------------
__global__ __launch_bounds__(512) void k_sg0(const int* __restrict__ deg,
                                             const int2* __restrict__ ebinF,
                                             const unsigned short* __restrict__ z0b,
                                             const float* __restrict__ b0,
                                             const float* __restrict__ W1,
                                             float* __restrict__ z1) {
    __shared__ int2 sorted[BCAPF];               // 37.9 KB
    __shared__ int scn[BK_NODES], dg[BK_NODES], run[BK_NODES];
    __shared__ int wtot[2], ecnt_s;
    __shared__ float b0s[16], w1s[16];
    const int tid  = threadIdx.x;
    const int lane = tid & 63, wid = tid >> 6;
    const int b    = blockIdx.x;
    if (tid < 16) { b0s[tid] = b0[tid]; w1s[tid] = W1[tid]; }

    int inc = 0, d_ = 0;
    if (tid < BK_NODES) {
        int v = b * BK_NODES + tid;
        d_ = (v < N_NODES) ? deg[v] : 0;
        dg[tid]  = d_;
        run[tid] = 0;
        inc = d_;
        #pragma unroll
        for (int off = 1; off < 64; off <<= 1) {
            int t = __shfl_up(inc, off);
            if (lane >= off) inc += t;
        }
        if (lane == 63) wtot[tid >> 6] = inc;
    }
    __syncthreads();
    if (tid < BK_NODES) {
        int base = (tid >= 64) ? wtot[0] : 0;
        scn[tid] = base + inc - d_;
        if (tid == BK_NODES - 1) ecnt_s = min(base + inc, BCAPF);
    }
    __syncthreads();

    const int ecnt = ecnt_s;
    const int2* eb = ebinF + (size_t)b * BCAPF;
    for (int i = tid; i < ecnt; i += 512) {
        int2 e  = eb[i];
        int  dl = e.y >> 17;
        int  p  = scn[dl] + atomicAdd(&run[dl], 1);
        if (p < BCAPF) sorted[p] = e;
    }
    __syncthreads();

    for (int n = wid; n < BK_NODES; n += 8) {
        const int v = b * BK_NODES + n;
        if (v >= N_NODES) continue;
        const int beg = scn[n];
        const int end = min(beg + dg[n], BCAPF);
        const int dv  = end - beg;
        const int f2  = lane & 7;
        const int g   = lane >> 3;
        float acc0 = 0.f, acc1 = 0.f;
        for (int j = g; j < dv; j += 16) {
            int2 e0 = sorted[beg + j];
            int  j1 = j + 8;
            int2 e1 = (j1 < dv) ? sorted[beg + j1] : make_int2(0, 0);
            unsigned u0 = *(const unsigned*)(z0b + (size_t)(e0.y & 0x1FFFF) * F_HID + f2 * 2);
            unsigned u1 = *(const unsigned*)(z0b + (size_t)(e1.y & 0x1FFFF) * F_HID + f2 * 2);
            float w0 = __int_as_float(e0.x), w1 = __int_as_float(e1.x);
            acc0 = fmaf(__uint_as_float(u0 << 16),         w0, acc0);
            acc1 = fmaf(__uint_as_float(u0 & 0xFFFF0000u), w0, acc1);
            acc0 = fmaf(__uint_as_float(u1 << 16),         w1, acc0);
            acc1 = fmaf(__uint_as_float(u1 & 0xFFFF0000u), w1, acc1);
        }
        acc0 += __shfl_xor(acc0, 8);  acc1 += __shfl_xor(acc1, 8);
        acc0 += __shfl_xor(acc0, 16); acc1 += __shfl_xor(acc1, 16);
        acc0 += __shfl_xor(acc0, 32); acc1 += __shfl_xor(acc1, 32);
        float cc = fmaxf(acc0 + b0s[f2 * 2], 0.f) * w1s[f2 * 2]
                 + fmaxf(acc1 + b0s[f2 * 2 + 1], 0.f) * w1s[f2 * 2 + 1];
        cc += __shfl_xor(cc, 1);
        cc += __shfl_xor(cc, 2);
        cc += __shfl_xor(cc, 4);
        if (lane == 0) z1[v] = cc;
    }
}

// ---------------------------------------------------------------------------
// K4: layer 1 from bucket-grouped ebinF: 1 LDS atomic/edge + fused sigmoid.
// ---------------------------------------------------------------------------
__global__ __launch_bounds__(256) void k_g1(const int* __restrict__ cursorF,
                                            const int2* __restrict__ ebinF,
                                            const float* __restrict__ z1,
                                            const float* __restrict__ b1,
                                            float* __restrict__ out) {
    __shared__ float acc[BK_NODES];
    const int tid = threadIdx.x;
    const int b   = blockIdx.x;
    if (tid < BK_NODES) acc[tid] = 0.f;
    __syncthreads();
    const int   ecnt = min(cursorF[b * CUR_STRIDE], BCAPF);
    const int2* eb   = ebinF + (size_t)b * BCAPF;
    for (int i = tid; i < ecnt; i += 512) {
        int2 e0 = eb[i];
        int  i1 = i + 256;
        int2 e1 = (i1 < ecnt) ? eb[i1] : make_int2(0, 0);
        float m0 = z1[e0.y & 0x1FFFF] * __int_as_float(e0.x);
        float m1 = z1[e1.y & 0x1FFFF] * __int_as_float(e1.x);
        atomicAdd(&acc[e0.y >> 17], m0);
        if (i1 < ecnt) atomicAdd(&acc[e1.y >> 17], m1);
    }
    __syncthreads();
    if (tid < BK_NODES) {
        int v = b * BK_NODES + tid;
        if (v < N_NODES) out[v] = 1.f / (1.f + expf(-(acc[tid] + b1[0])));
    }
}

extern "C" void kernel_launch(void* const* d_in, const int* in_sizes, int n_in,
                              void* d_out, int out_size, void* d_ws, size_t ws_size,
                              hipStream_t stream) {
    const float* x   = (const float*)d_in[0];
    const int*   src = (const int*)d_in[1];
    const int*   dst = (const int*)d_in[2];
    const float* ew  = (const float*)d_in[3];
    const float* W0  = (const float*)d_in[4];
    const float* b0  = (const float*)d_in[5];
    const float* W1  = (const float*)d_in[6];
    const float* b1  = (const float*)d_in[7];
    float* out = (float*)d_out;

    // Workspace (~61 MB): z0b | z1 | deg | cursorC | cursorF | ebinC | ebinF
    unsigned short* z0b = (unsigned short*)d_ws;                 // 3.2 MB
    float* z1      = (float*)(z0b + (size_t)N_NODES * F_HID);    // 400 KB
    int*   deg     = (int*)(z1 + N_NODES);                       // 400 KB
    int*   cursorC = deg + N_NODES;                              // 6.3 KB
    int*   cursorF = cursorC + NBC * CUR_STRIDE;                 // 50 KB
    int2*  ebinC   = (int2*)(cursorF + NB * CUR_STRIDE);         // 27.3 MB
    int2*  ebinF   = ebinC + (size_t)NBC * BCAPC;                // 29.6 MB

    hipMemsetAsync(deg, 0,
                   ((size_t)N_NODES + (size_t)(NBC + NB) * CUR_STRIDE) * sizeof(int),
                   stream);

    k_bin1<<<NCH1, 512, 0, stream>>>(src, dst, ew, cursorC, ebinC);
    k_mid <<<GRID_MID, 256, 0, stream>>>(cursorC, ebinC, cursorF, ebinF, deg,
                                         x, W0, z0b);
    k_sg0 <<<NB, 512, 0, stream>>>(deg, ebinF, z0b, b0, W1, z1);
    k_g1  <<<NB, 256, 0, stream>>>(cursorF, ebinF, z1, b1, out);
}

// Round 14
// 125.066 us; speedup vs baseline: 1.1004x; 1.0042x over previous
//
#include <hip/hip_runtime.h>

#define N_NODES 100000
#define N_EDGES 3200000
#define F_IN 128
#define F_HID 16

// fine buckets (consumer-facing)
#define BK_LG 7
#define BK_NODES 128
#define NB ((N_NODES + BK_NODES - 1) / BK_NODES)      // 782
#define BCAPF 4736                                    // avg 4093, +10 sigma
// coarse buckets (pass-1)
#define CLG 10
#define CNODES 1024
#define NBC ((N_NODES + CNODES - 1) / CNODES)         // 98
#define NBC_P 128
#define BCAPC 34816                                   // avg 32768, +11 sigma
#define CHUNK1 4096                                   // pass-1 chunk (512 threads)
#define NCH1 ((N_EDGES + CHUNK1 - 1) / CHUNK1)        // 782
#define CHUNKM 2048                                   // pass-2 chunk (256 threads)
#define CPB2 ((BCAPC + CHUNKM - 1) / CHUNKM)          // 17
#define NMB (NBC * CPB2)                              // 1666 bin2-role blocks
#define NXB ((N_NODES + 63) / 64)                     // 1563 xw0 tiles
#define PAIRED (2 * NXB)                              // 3126
#define GRID_MID (NMB + NXB)                          // 3229
#define CUR_STRIDE 16
#define ZTOT (N_NODES + NB * CUR_STRIDE)              // deg + cursorF ints

__device__ __forceinline__ unsigned short f2bf_rne(float f) {
    unsigned u = __float_as_uint(f);
    u += 0x7FFFu + ((u >> 16) & 1u);
    return (unsigned short)(u >> 16);
}

// ---------------------------------------------------------------------------
// K0: zero cursorC (tiny; replaces the pathologically slow hipMemsetAsync).
// ---------------------------------------------------------------------------
__global__ __launch_bounds__(256) void k_zc(int* __restrict__ cursorC) {
    int i = blockIdx.x * 256 + threadIdx.x;
    if (i < NBC * CUR_STRIDE) cursorC[i] = 0;
}

// ---------------------------------------------------------------------------
// K1: pass-1 bin into coarse 1024-node buckets. 4096 edges/block, 512 thr,
// WAVE-MAJOR replicated counters cntw[w][b] (consecutive addrs -> no bank
// aliasing, no cross-wave contention). Prologue stripe-zeroes deg+cursorF
// (consumed only by later kernels).
// ---------------------------------------------------------------------------
__global__ __launch_bounds__(512) void k_bin1(const int* __restrict__ src,
                                              const int* __restrict__ dst,
                                              const float* __restrict__ ew,
                                              int* __restrict__ cursorC,
                                              int2* __restrict__ ebinC,
                                              int* __restrict__ deg,
                                              int* __restrict__ cursorF) {
    __shared__ int2 stage[CHUNK1];                 // 32 KB
    __shared__ unsigned char sbid[CHUNK1];         // 4 KB
    __shared__ int cntw[8 * NBC_P];                // [wave][bucket]
    __shared__ int runw[8 * NBC_P];
    __shared__ int basew[8 * NBC_P];
    __shared__ int cnt[NBC_P], excl[NBC_P], gb[NBC_P], alw[NBC_P];
    __shared__ int wtot[2];
    const int tid  = threadIdx.x;
    const int lane = tid & 63, wid = tid >> 6;     // 8 waves
    const int e0   = blockIdx.x * CHUNK1;
    const int nch  = min(CHUNK1, N_EDGES - e0);

    // stripe-zero deg + cursorF (1 element/thread across the grid)
    for (int i = blockIdx.x * 512 + tid; i < ZTOT; i += NCH1 * 512) {
        if (i < N_NODES) deg[i] = 0;
        else             cursorF[i - N_NODES] = 0;
    }

    for (int i = tid; i < 8 * NBC_P; i += 512) { cntw[i] = 0; runw[i] = 0; }
    __syncthreads();

    // load + per-wave count
    int es[8], eb[8], edl[8]; float ww[8];
    #pragma unroll
    for (int k = 0; k < 8; ++k) {
        int idx = k * 512 + tid;
        if (idx < nch) {
            int e = e0 + idx;
            int d = dst[e];
            es[k]  = src[e];
            ww[k]  = ew[e];
            eb[k]  = d >> CLG;
            edl[k] = d & (CNODES - 1);
            atomicAdd(&cntw[wid * NBC_P + eb[k]], 1);
        } else {
            eb[k] = -1;
        }
    }
    __syncthreads();

    // per-bucket totals
    if (tid < NBC_P) {
        int t = 0;
        #pragma unroll
        for (int w = 0; w < 8; ++w) t += cntw[w * NBC_P + tid];
        cnt[tid] = t;
    }
    __syncthreads();

    // exclusive scan of cnt[0..128) via 2-wave shuffle; cursor reserve
    int inc = 0, c_ = 0;
    if (tid < NBC_P) {
        c_ = cnt[tid];
        inc = c_;
        #pragma unroll
        for (int off = 1; off < 64; off <<= 1) {
            int t = __shfl_up(inc, off);
            if (lane >= off) inc += t;
        }
        if (lane == 63) wtot[tid >> 6] = inc;
    }
    __syncthreads();
    if (tid < NBC_P) {
        int base = (tid >= 64) ? wtot[0] : 0;
        excl[tid] = base + inc - c_;
    }
    if (tid < NBC) {
        int c = cnt[tid];
        if (c > 0) {
            int old = atomicAdd(&cursorC[tid * CUR_STRIDE], c);
            int a = BCAPC - old;
            a = (a < 0) ? 0 : ((a > c) ? c : a);
            alw[tid] = a;
            gb[tid]  = tid * BCAPC + old;
        } else {
            alw[tid] = 0;
            gb[tid]  = tid * BCAPC;
        }
    }
    __syncthreads();

    // per-(wave,bucket) bases
    if (tid < NBC_P) {
        int bb = excl[tid];
        #pragma unroll
        for (int w = 0; w < 8; ++w) { basew[w * NBC_P + tid] = bb; bb += cntw[w * NBC_P + tid]; }
    }
    __syncthreads();

    // place (unique slots; same-wave atomics on consecutive addresses)
    #pragma unroll
    for (int k = 0; k < 8; ++k) {
        if (eb[k] >= 0) {
            int b = eb[k];
            int p = basew[wid * NBC_P + b] + atomicAdd(&runw[wid * NBC_P + b], 1);
            stage[p] = make_int2(__float_as_int(ww[k]), es[k] | (edl[k] << 17));
            sbid[p]  = (unsigned char)b;
        }
    }
    __syncthreads();

    // flush: runs of ~42 edges per bucket -> near-coalesced
    for (int s = tid; s < nch; s += 512) {
        int b   = sbid[s];
        int off = s - excl[b];
        if (off < alw[b]) ebinC[(size_t)gb[b] + off] = stage[s];
    }
}

// ---------------------------------------------------------------------------
// K2 (fused, 24.8KB union -> 6 blocks/CU):
//   role A (bin2): split one 2048-edge coarse chunk 8-ways into fine buckets
//                  + per-node degree histogram (LDS dcnt -> striped atomics)
//   role B (xw0):  64-row x@W0 tile (x staged bf16) -> z0b
// ---------------------------------------------------------------------------
__global__ __launch_bounds__(256) void k_mid(const int* __restrict__ cursorC,
                                             const int2* __restrict__ ebinC,
                                             int* __restrict__ cursorF,
                                             int2* __restrict__ ebinF,
                                             int* __restrict__ deg,
                                             const float* __restrict__ x,
                                             const float* __restrict__ W0,
                                             unsigned short* __restrict__ z0b) {
    __shared__ __align__(16) char smem[24832];
    const int tid = threadIdx.x;
    const int bid = blockIdx.x;
    int rid; bool isBin;
    if (bid < PAIRED) { isBin = (bid & 1) == 0; rid = bid >> 1; }
    else              { isBin = true; rid = NXB + (bid - PAIRED); }

    if (!isBin) {
        // ------------------- xw0 role (bf16-staged x) -------------------
        unsigned short* xsb = (unsigned short*)smem;      // [64][130] bf16
        float* w0s = (float*)(smem + 16640);              // [128*16] f32
        for (int i = tid; i < F_IN * F_HID; i += 256) w0s[i] = W0[i];
        const int row0 = rid * 64;
        for (int i = tid; i < 64 * 32; i += 256) {
            int r = i >> 5, c4 = i & 31;
            float4 v = make_float4(0.f, 0.f, 0.f, 0.f);
            int row = row0 + r;
            if (row < N_NODES) v = ((const float4*)(x + (size_t)row * F_IN))[c4];
            *(ushort2*)(xsb + r * 130 + c4 * 4)     = make_ushort2(f2bf_rne(v.x), f2bf_rne(v.y));
            *(ushort2*)(xsb + r * 130 + c4 * 4 + 2) = make_ushort2(f2bf_rne(v.z), f2bf_rne(v.w));
        }
        __syncthreads();
        const int r  = tid & 63;
        const int cg = tid >> 6;
        float a0 = 0.f, a1 = 0.f, a2 = 0.f, a3 = 0.f;
        #pragma unroll 4
        for (int k = 0; k < F_IN; k += 2) {
            unsigned u = *(const unsigned*)(xsb + r * 130 + k);
            float xv0 = __uint_as_float(u << 16);
            float xv1 = __uint_as_float(u & 0xFFFF0000u);
            const float* wr0 = w0s + k * F_HID + cg * 4;
            const float* wr1 = wr0 + F_HID;
            a0 = fmaf(xv0, wr0[0], a0); a1 = fmaf(xv0, wr0[1], a1);
            a2 = fmaf(xv0, wr0[2], a2); a3 = fmaf(xv0, wr0[3], a3);
            a0 = fmaf(xv1, wr1[0], a0); a1 = fmaf(xv1, wr1[1], a1);
            a2 = fmaf(xv1, wr1[2], a2); a3 = fmaf(xv1, wr1[3], a3);
        }
        int row = row0 + r;
        if (row < N_NODES) {
            ushort4 p = make_ushort4(f2bf_rne(a0), f2bf_rne(a1),
                                     f2bf_rne(a2), f2bf_rne(a3));
            *(ushort4*)(z0b + (size_t)row * F_HID + cg * 4) = p;
        }
    } else {
        // ------------------- bin2 role -------------------
        int2* stage = (int2*)smem;                             // 16384 B
        unsigned char* sbid = (unsigned char*)(smem + 16384);  // 2048 B
        int* dcnt   = (int*)(smem + 18432);                    // 1024 ints
        int* cntw   = (int*)(smem + 22528);                    // 32
        int* runw   = (int*)(smem + 22656);                    // 32
        int* base   = (int*)(smem + 22784);                    // 32
        int* totals = (int*)(smem + 23040);                    // 8
        int* excl_s = (int*)(smem + 23072);                    // 8
        int* gb8    = (int*)(smem + 23104);                    // 8
        int* alw8   = (int*)(smem + 23136);                    // 8
        const int wid = tid >> 6;                              // 0..3
        const int c   = rid / CPB2;
        const int ck  = rid % CPB2;
        const int ecnt = min(cursorC[c * CUR_STRIDE], BCAPC);
        const int beg  = ck * CHUNKM;
        const int n2   = min(CHUNKM, ecnt - beg);
        if (n2 <= 0) return;                                   // uniform exit
        const int2* eC = ebinC + (size_t)c * BCAPC + beg;

        if (tid < 32) { cntw[tid] = 0; runw[tid] = 0; }
        for (int i = tid; i < CNODES; i += 256) dcnt[i] = 0;
        __syncthreads();

        int fid[8]; int2 pk[8];
        #pragma unroll
        for (int k = 0; k < 8; ++k) {
            int idx = k * 256 + tid;
            if (idx < n2) {
                int2 e = eC[idx];
                int dlc = e.y >> 17;
                int f   = dlc >> BK_LG;
                fid[k]  = f;
                pk[k]   = make_int2(e.x, (e.y & 0x1FFFF) | ((dlc & (BK_NODES - 1)) << 17));
                atomicAdd(&cntw[f * 4 + wid], 1);
                atomicAdd(&dcnt[dlc], 1);
            } else {
                fid[k] = -1;
            }
        }
        __syncthreads();

        if (tid < 8) {
            int t = 0;
            #pragma unroll
            for (int w = 0; w < 4; ++w) t += cntw[tid * 4 + w];
            totals[tid] = t;
        }
        __syncthreads();
        if (tid < 8) {
            int e = 0;
            for (int f = 0; f < 8; ++f) if (f < tid) e += totals[f];
            excl_s[tid] = e;
            int t = totals[tid];
            int fb = c * 8 + tid;
            if (t > 0 && fb < NB) {
                int old = atomicAdd(&cursorF[fb * CUR_STRIDE], t);
                int a = BCAPF - old;
                a = (a < 0) ? 0 : ((a > t) ? t : a);
                alw8[tid] = a;
                gb8[tid]  = fb * BCAPF + old;
            } else {
                alw8[tid] = 0;
                gb8[tid]  = 0;
            }
        }
        __syncthreads();
        if (tid < 32) {
            int f = tid >> 2, w = tid & 3;
            int bb = excl_s[f];
            for (int w2 = 0; w2 < 4; ++w2) if (w2 < w) bb += cntw[f * 4 + w2];
            base[tid] = bb;
        }
        __syncthreads();

        #pragma unroll
        for (int k = 0; k < 8; ++k) {
            if (fid[k] >= 0) {
                int slot = fid[k] * 4 + wid;
                int p = base[slot] + atomicAdd(&runw[slot], 1);
                stage[p] = pk[k];
                sbid[p]  = (unsigned char)fid[k];
            }
        }
        __syncthreads();

        for (int s = tid; s < n2; s += 256) {
            int f   = sbid[s];
            int off = s - excl_s[f];
            if (off < alw8[f]) ebinF[(size_t)gb8[f] + off] = stage[s];
        }

        for (int i = tid; i < CNODES; i += 256) {
            int d = dcnt[i];
            int v = c * CNODES + i;
            if (d > 0 && v < N_NODES) atomicAdd(&deg[v], d);
        }
    }
}

// ---------------------------------------------------------------------------
// K3: gather layer 0 with direct-place LDS sort (deg precomputed).
// ---------------------------------------------------------------------------
__global__ __launch_bounds__(512) void k_sg0(const int* __restrict__ deg,
                                             const int2* __restrict__ ebinF,
                                             const unsigned short* __restrict__ z0b,
                                             const float* __restrict__ b0,
                                             const float* __restrict__ W1,
                                             float* __restrict__ z1) {
    __shared__ int2 sorted[BCAPF];               // 37.9 KB
    __shared__ int scn[BK_NODES], dg[BK_NODES], run[BK_NODES];
    __shared__ int wtot[2], ecnt_s;
    __shared__ float b0s[16], w1s[16];
    const int tid  = threadIdx.x;
    const int lane = tid & 63, wid = tid >> 6;
    const int b    = blockIdx.x;
    if (tid < 16) { b0s[tid] = b0[tid]; w1s[tid] = W1[tid]; }

    int inc = 0, d_ = 0;
    if (tid < BK_NODES) {
        int v = b * BK_NODES + tid;
        d_ = (v < N_NODES) ? deg[v] : 0;
        dg[tid]  = d_;
        run[tid] = 0;
        inc = d_;
        #pragma unroll
        for (int off = 1; off < 64; off <<= 1) {
            int t = __shfl_up(inc, off);
            if (lane >= off) inc += t;
        }
        if (lane == 63) wtot[tid >> 6] = inc;
    }
    __syncthreads();
    if (tid < BK_NODES) {
        int base = (tid >= 64) ? wtot[0] : 0;
        scn[tid] = base + inc - d_;
        if (tid == BK_NODES - 1) ecnt_s = min(base + inc, BCAPF);
    }
    __syncthreads();

    const int ecnt = ecnt_s;
    const int2* eb = ebinF + (size_t)b * BCAPF;
    for (int i = tid; i < ecnt; i += 512) {
        int2 e  = eb[i];
        int  dl = e.y >> 17;
        int  p  = scn[dl] + atomicAdd(&run[dl], 1);
        if (p < BCAPF) sorted[p] = e;
    }
    __syncthreads();

    for (int n = wid; n < BK_NODES; n += 8) {
        const int v = b * BK_NODES + n;
        if (v >= N_NODES) continue;
        const int beg = scn[n];
        const int end = min(beg + dg[n], BCAPF);
        const int dv  = end - beg;
        const int f2  = lane & 7;
        const int g   = lane >> 3;
        float acc0 = 0.f, acc1 = 0.f;
        for (int j = g; j < dv; j += 16) {
            int2 e0 = sorted[beg + j];
            int  j1 = j + 8;
            int2 e1 = (j1 < dv) ? sorted[beg + j1] : make_int2(0, 0);
            unsigned u0 = *(const unsigned*)(z0b + (size_t)(e0.y & 0x1FFFF) * F_HID + f2 * 2);
            unsigned u1 = *(const unsigned*)(z0b + (size_t)(e1.y & 0x1FFFF) * F_HID + f2 * 2);
            float w0 = __int_as_float(e0.x), w1 = __int_as_float(e1.x);
            acc0 = fmaf(__uint_as_float(u0 << 16),         w0, acc0);
            acc1 = fmaf(__uint_as_float(u0 & 0xFFFF0000u), w0, acc1);
            acc0 = fmaf(__uint_as_float(u1 << 16),         w1, acc0);
            acc1 = fmaf(__uint_as_float(u1 & 0xFFFF0000u), w1, acc1);
        }
        acc0 += __shfl_xor(acc0, 8);  acc1 += __shfl_xor(acc1, 8);
        acc0 += __shfl_xor(acc0, 16); acc1 += __shfl_xor(acc1, 16);
        acc0 += __shfl_xor(acc0, 32); acc1 += __shfl_xor(acc1, 32);
        float cc = fmaxf(acc0 + b0s[f2 * 2], 0.f) * w1s[f2 * 2]
                 + fmaxf(acc1 + b0s[f2 * 2 + 1], 0.f) * w1s[f2 * 2 + 1];
        cc += __shfl_xor(cc, 1);
        cc += __shfl_xor(cc, 2);
        cc += __shfl_xor(cc, 4);
        if (lane == 0) z1[v] = cc;
    }
}

// ---------------------------------------------------------------------------
// K4: layer 1 from bucket-grouped ebinF: 1 LDS atomic/edge + fused sigmoid.
// ---------------------------------------------------------------------------
__global__ __launch_bounds__(256) void k_g1(const int* __restrict__ cursorF,
                                            const int2* __restrict__ ebinF,
                                            const float* __restrict__ z1,
                                            const float* __restrict__ b1,
                                            float* __restrict__ out) {
    __shared__ float acc[BK_NODES];
    const int tid = threadIdx.x;
    const int b   = blockIdx.x;
    if (tid < BK_NODES) acc[tid] = 0.f;
    __syncthreads();
    const int   ecnt = min(cursorF[b * CUR_STRIDE], BCAPF);
    const int2* eb   = ebinF + (size_t)b * BCAPF;
    for (int i = tid; i < ecnt; i += 512) {
        int2 e0 = eb[i];
        int  i1 = i + 256;
        int2 e1 = (i1 < ecnt) ? eb[i1] : make_int2(0, 0);
        float m0 = z1[e0.y & 0x1FFFF] * __int_as_float(e0.x);
        float m1 = z1[e1.y & 0x1FFFF] * __int_as_float(e1.x);
        atomicAdd(&acc[e0.y >> 17], m0);
        if (i1 < ecnt) atomicAdd(&acc[e1.y >> 17], m1);
    }
    __syncthreads();
    if (tid < BK_NODES) {
        int v = b * BK_NODES + tid;
        if (v < N_NODES) out[v] = 1.f / (1.f + expf(-(acc[tid] + b1[0])));
    }
}

extern "C" void kernel_launch(void* const* d_in, const int* in_sizes, int n_in,
                              void* d_out, int out_size, void* d_ws, size_t ws_size,
                              hipStream_t stream) {
    const float* x   = (const float*)d_in[0];
    const int*   src = (const int*)d_in[1];
    const int*   dst = (const int*)d_in[2];
    const float* ew  = (const float*)d_in[3];
    const float* W0  = (const float*)d_in[4];
    const float* b0  = (const float*)d_in[5];
    const float* W1  = (const float*)d_in[6];
    const float* b1  = (const float*)d_in[7];
    float* out = (float*)d_out;

    // Workspace (~61 MB): z0b | z1 | deg | cursorC | cursorF | ebinC | ebinF
    unsigned short* z0b = (unsigned short*)d_ws;                 // 3.2 MB
    float* z1      = (float*)(z0b + (size_t)N_NODES * F_HID);    // 400 KB
    int*   deg     = (int*)(z1 + N_NODES);                       // 400 KB
    int*   cursorC = deg + N_NODES;                              // 6.3 KB
    int*   cursorF = cursorC + NBC * CUR_STRIDE;                 // 50 KB
    int2*  ebinC   = (int2*)(cursorF + NB * CUR_STRIDE);         // 27.3 MB
    int2*  ebinF   = ebinC + (size_t)NBC * BCAPC;                // 29.6 MB

    k_zc  <<<(NBC * CUR_STRIDE + 255) / 256, 256, 0, stream>>>(cursorC);
    k_bin1<<<NCH1, 512, 0, stream>>>(src, dst, ew, cursorC, ebinC, deg, cursorF);
    k_mid <<<GRID_MID, 256, 0, stream>>>(cursorC, ebinC, cursorF, ebinF, deg,
                                         x, W0, z0b);
    k_sg0 <<<NB, 512, 0, stream>>>(deg, ebinF, z0b, b0, W1, z1);
    k_g1  <<<NB, 256, 0, stream>>>(cursorF, ebinF, z1, b1, out);
}